// Round 4
// baseline (374.010 us; speedup 1.0000x reference)
//
#include <hip/hip_runtime.h>

#define NB 8
#define NC 256
#define DF 16384
#define KCL 16
#define SPLITS 16
#define KC (DF / SPLITS)     // 1024
#define BK 32
#define ITERS (KC / BK)      // 32
#define NPAIR 3              // 128x128 upper-tri pairs: (0,0),(0,1),(1,1)
#define GEMM_BLOCKS (NPAIR * 2 * NB * SPLITS)   // 6*8*16 = 768

typedef _Float16 half8 __attribute__((ext_vector_type(8)));
typedef float floatx4 __attribute__((ext_vector_type(4)));

__device__ const int TItab[NPAIR] = {0,0,1};
__device__ const int TJtab[NPAIR] = {0,1,1};

// ------------- argmax over 256 threads: wave-shuffle + 2 barriers ---------------
// first-occurrence semantics (ties -> smallest index), matches jnp.argmax
__device__ __forceinline__ int argmax256w(float v, float* sv, int* si) {
  int t = threadIdx.x;
  float bv = v; int bi = t;
  #pragma unroll
  for (int s = 32; s >= 1; s >>= 1) {
    float ov = __shfl_down(bv, s);
    int   oi = __shfl_down(bi, s);
    if (ov > bv || (ov == bv && oi < bi)) { bv = ov; bi = oi; }
  }
  int w = t >> 6;
  if ((t & 63) == 0) { sv[w] = bv; si[w] = bi; }
  __syncthreads();
  float rbv = sv[0]; int rbi = si[0];
  #pragma unroll
  for (int k = 1; k < 4; ++k) {
    float ov = sv[k]; int oi = si[k];
    if (ov > rbv || (ov == rbv && oi < rbi)) { rbv = ov; rbi = oi; }
  }
  __syncthreads();   // protect sv/si for next call
  return rbi;
}

// hi/lo f16 split of 8 f32 (pure per-element function -> bit-identical anywhere)
__device__ __forceinline__ void cvt8(const float4& r0, const float4& r1,
                                     half8& hh, half8& ll) {
  float f[8] = {r0.x, r0.y, r0.z, r0.w, r1.x, r1.y, r1.z, r1.w};
  #pragma unroll
  for (int e = 0; e < 8; ++e) {
    _Float16 h = (_Float16)f[e];
    hh[e] = h; ll[e] = (_Float16)(f[e] - (float)h);
  }
}

// ---------------- K1: fused [gemm 768 blocks | pos-FPS block 768] ----------------
// gemm: NO LDS, NO barriers. Each wave owns a 64x32 output tile and loads its MFMA
// fragments DIRECTLY from global (lane->(row,k) matches the 16x16x32 frag layout:
// 16 rows x 128B contiguous per load). The 2x cross-wave tile redundancy is served
// by L1/L2 (XCD remap keeps each (b,sp) group on one XCD's L2). Removing the
// 2-barrier-per-K-step lockstep is the point: rounds 1-3 showed no pipe >15% busy
// while waves sat in barrier/waitcnt serialization.
__global__ __launch_bounds__(256, 2) void k_gemm_pre(const float* __restrict__ ff,
                                                     const float* __restrict__ pe,
                                                     float* __restrict__ Pp,
                                                     float* __restrict__ centers0,
                                                     float* __restrict__ rs) {
  __shared__ float sm[1056];   // pos-FPS scratch only (gemm blocks never touch it)

  const int bid = blockIdx.x;
  const int tid = threadIdx.x;

  if (bid == GEMM_BLOCKS) {
    // ---- pos-FPS (256 threads) ----
    float* px = sm;        float* py = sm + 256;
    float* pz = sm + 512;  float* pn = sm + 768;
    float* sv = sm + 1024; int*   si = (int*)(sm + 1028);
    int* fpsIdx = (int*)(sm + 1032);
    const int t = tid;
    for (int i = t; i < NB * NC; i += 256) rs[i] = 0.f;   // zero rs (ws poisoned)
    float x = pe[t * 3 + 0], y = pe[t * 3 + 1], z = pe[t * 3 + 2];
    float n = x * x + y * y + z * z;
    px[t] = x; py[t] = y; pz[t] = z; pn[t] = n;
    __syncthreads();
    float rsum = 0.f;
    for (int j = 0; j < NC; ++j) {
      float dot = x * px[j] + y * py[j] + z * pz[j];
      rsum += sqrtf(fmaxf(n + pn[j] - 2.f * dot, 0.f));
    }
    int start = argmax256w(rsum, sv, si);
    if (t == 0) fpsIdx[0] = start;
    float dot0 = x * px[start] + y * py[start] + z * pz[start];
    float mind = sqrtf(fmaxf(n + pn[start] - 2.f * dot0, 0.f));
    for (int it = 1; it < KCL; ++it) {
      int far = argmax256w(mind, sv, si);
      if (t == 0) fpsIdx[it] = far;
      float dot = x * px[far] + y * py[far] + z * pz[far];
      mind = fminf(mind, sqrtf(fmaxf(n + pn[far] - 2.f * dot, 0.f)));
    }
    __syncthreads();
    if (t < KCL) {
      int p = fpsIdx[t];
      centers0[t * 3 + 0] = px[p];
      centers0[t * 3 + 1] = py[p];
      centers0[t * 3 + 2] = pz[p];
    }
    return;
  }

  // ---- gemm block ----
  // XCD-aware remap (bijective: 768 = 8 XCD * 16 groups * 6 tc).
  const int x    = bid & 7;
  const int slot = bid >> 3;      // 0..95
  const int tc   = slot % 6;
  const int u    = slot / 6;      // 0..15
  const int gi   = x * 16 + u;    // 0..127
  const int b    = gi & 7;
  const int sp   = gi >> 3;

  const int pair = tc >> 1, ch = tc & 1;
  const int ti = TItab[pair], tj = TJtab[pair];
  const bool diag = (ti == tj);

  const int wave = tid >> 6, lane = tid & 63;
  const int wr = wave >> 1, wc = wave & 1;    // 4 waves: 2 row-strips(64) x 2 col-strips(32)
  const int lrow = lane & 15, q = lane >> 4;

  // Per-lane fragment pointers: row = frag row (lane&15), k-offset = (lane>>4)*8.
  // Matches the LDS-tile read pattern of rounds 0-3 exactly -> identical values.
  const float* pA[4];
  const float* pB[2];
  #pragma unroll
  for (int i = 0; i < 4; ++i)
    pA[i] = ff + (size_t)(b * NC + ti * 128 + wr * 64 + i * 16 + lrow) * DF
               + (size_t)sp * KC + q * 8;
  #pragma unroll
  for (int j = 0; j < 2; ++j)
    pB[j] = ff + (size_t)(b * NC + tj * 128 + ch * 64 + wc * 32 + j * 16 + lrow) * DF
               + (size_t)sp * KC + q * 8;

  floatx4 a1[4][2], c23[4][2];
  #pragma unroll
  for (int i = 0; i < 4; ++i)
    #pragma unroll
    for (int j = 0; j < 2; ++j) { a1[i][j] = (floatx4)0.f; c23[i][j] = (floatx4)0.f; }

  // prefetch it=0
  float4 ra[4][2], rb[2][2];
  #pragma unroll
  for (int i = 0; i < 4; ++i) {
    ra[i][0] = *(const float4*)(pA[i]);
    ra[i][1] = *(const float4*)(pA[i] + 4);
    pA[i] += BK;
  }
  #pragma unroll
  for (int j = 0; j < 2; ++j) {
    rb[j][0] = *(const float4*)(pB[j]);
    rb[j][1] = *(const float4*)(pB[j] + 4);
    pB[j] += BK;
  }

  for (int it = 0; it < ITERS; ++it) {
    // convert current stage to hi/lo fragments (pure function of the f32 values)
    half8 ah[4], al[4], bh[2], bl[2];
    #pragma unroll
    for (int i = 0; i < 4; ++i) cvt8(ra[i][0], ra[i][1], ah[i], al[i]);
    #pragma unroll
    for (int j = 0; j < 2; ++j) cvt8(rb[j][0], rb[j][1], bh[j], bl[j]);

    // prefetch next K-step (no barriers anywhere -> loads fly under MFMAs)
    if (it + 1 < ITERS) {
      #pragma unroll
      for (int i = 0; i < 4; ++i) {
        ra[i][0] = *(const float4*)(pA[i]);
        ra[i][1] = *(const float4*)(pA[i] + 4);
        pA[i] += BK;
      }
      #pragma unroll
      for (int j = 0; j < 2; ++j) {
        rb[j][0] = *(const float4*)(pB[j]);
        rb[j][1] = *(const float4*)(pB[j] + 4);
        pB[j] += BK;
      }
    }

    __builtin_amdgcn_s_setprio(1);
    #pragma unroll
    for (int i = 0; i < 4; ++i) {
      #pragma unroll
      for (int j = 0; j < 2; ++j) {
        a1[i][j]  = __builtin_amdgcn_mfma_f32_16x16x32_f16(ah[i], bh[j], a1[i][j], 0, 0, 0);
        c23[i][j] = __builtin_amdgcn_mfma_f32_16x16x32_f16(ah[i], bl[j], c23[i][j], 0, 0, 0);
        c23[i][j] = __builtin_amdgcn_mfma_f32_16x16x32_f16(al[i], bh[j], c23[i][j], 0, 0, 0);
      }
    }
    __builtin_amdgcn_s_setprio(0);
  }

  // epilogue: S = a1 + c23. Diag 128x128 blocks fully covered by both halves -> no mirror.
  float* Pb = Pp + (size_t)(sp * NB + b) * NC * NC;
  #pragma unroll
  for (int i = 0; i < 4; ++i) {
    int grow = ti * 128 + wr * 64 + i * 16 + q * 4;
    #pragma unroll
    for (int j = 0; j < 2; ++j) {
      int gcol = tj * 128 + ch * 64 + wc * 32 + j * 16 + lrow;
      float4 v;
      v.x = a1[i][j][0] + c23[i][j][0];
      v.y = a1[i][j][1] + c23[i][j][1];
      v.z = a1[i][j][2] + c23[i][j][2];
      v.w = a1[i][j][3] + c23[i][j][3];
      Pb[(size_t)(grow + 0) * NC + gcol] = v.x;
      Pb[(size_t)(grow + 1) * NC + gcol] = v.y;
      Pb[(size_t)(grow + 2) * NC + gcol] = v.z;
      Pb[(size_t)(grow + 3) * NC + gcol] = v.w;
      if (!diag) *(float4*)&Pb[(size_t)gcol * NC + grow] = v;  // mirror (lower block)
    }
  }
}

// ---------------- K2: diag + formD + column partial sums (fused) -----------------
__global__ __launch_bounds__(256) void k_formD(const float* __restrict__ Pp,
                                               float* __restrict__ Db,
                                               float* __restrict__ rs) {
  __shared__ float dg_s[NC];
  const int t = threadIdx.x;
  const int b = blockIdx.x >> 5, i0 = (blockIdx.x & 31) * 8;
  float s = 0.f;
  #pragma unroll
  for (int sp = 0; sp < SPLITS; ++sp)
    s += Pp[((size_t)(sp * NB + b) * NC + t) * NC + t];
  dg_s[t] = s;
  __syncthreads();
  float colsum = 0.f;
  for (int ii = 0; ii < 8; ++ii) {
    int i = i0 + ii;
    float acc = 0.f;
    #pragma unroll
    for (int sp = 0; sp < SPLITS; ++sp)
      acc += Pp[((size_t)(sp * NB + b) * NC + i) * NC + t];
    float d2 = dg_s[i] + dg_s[t] - 2.f * acc;
    float d = sqrtf(fmaxf(d2, 0.f));
    Db[((size_t)b * NC + i) * NC + t] = d;
    colsum += d;
  }
  atomicAdd(&rs[b * NC + t], colsum);
}

// ---------------- K3: per-batch FPS on Db (8 blocks), rs precomputed -------------
__global__ __launch_bounds__(256) void k_fps_b(const float* __restrict__ Db,
                                               const float* __restrict__ rs,
                                               const float* __restrict__ pe,
                                               float* __restrict__ ccoord) {
  int b = blockIdx.x, t = threadIdx.x;
  const float* D = Db + (size_t)b * NC * NC;
  __shared__ float sv[4]; __shared__ int si[4];
  __shared__ int fpsIdx[KCL];
  int start = argmax256w(rs[b * NC + t], sv, si);
  if (t == 0) fpsIdx[0] = start;
  float mind = D[start * NC + t];   // symmetric row==col
  for (int it = 1; it < KCL; ++it) {
    int far = argmax256w(mind, sv, si);
    if (t == 0) fpsIdx[it] = far;
    mind = fminf(mind, D[far * NC + t]);
  }
  __syncthreads();
  if (t < KCL) {
    int p = fpsIdx[t];
    ccoord[(b * KCL + t) * 3 + 0] = pe[(b * NC + p) * 3 + 0];
    ccoord[(b * KCL + t) * 3 + 1] = pe[(b * NC + p) * 3 + 1];
    ccoord[(b * KCL + t) * 3 + 2] = pe[(b * NC + p) * 3 + 2];
  }
}

// ---------------- K4: temp_assign + seg-means + matching + update + capacity -----
__global__ __launch_bounds__(256) void k_final(const float* __restrict__ pe,
                                               const float* __restrict__ ccoord,
                                               const float* __restrict__ centers0,
                                               int* __restrict__ outp) {
  __shared__ float cc[NB * KCL * 3];
  __shared__ float cn[NB * KCL];
  __shared__ float sums[KCL][3];
  __shared__ int cnts[KCL];
  __shared__ float avg[KCL][3];
  __shared__ float an[KCL];
  __shared__ float c0[KCL * 3];
  __shared__ float c1x[KCL], c1y[KCL], c1z[KCL], c1n[KCL];
  __shared__ int order[NC][KCL];
  int t = threadIdx.x;
  for (int i = t; i < NB * KCL * 3; i += 256) cc[i] = ccoord[i];
  if (t < KCL * 3) c0[t] = centers0[t];
  if (t < KCL) { sums[t][0] = 0.f; sums[t][1] = 0.f; sums[t][2] = 0.f; cnts[t] = 0; }
  __syncthreads();
  if (t < NB * KCL) {
    float x = cc[t * 3], y = cc[t * 3 + 1], z = cc[t * 3 + 2];
    cn[t] = x * x + y * y + z * z;
  }
  __syncthreads();
  for (int b = 0; b < NB; ++b) {
    int p = b * NC + t;
    float x = pe[p * 3], y = pe[p * 3 + 1], z = pe[p * 3 + 2];
    float n = x * x + y * y + z * z;
    float best = 3.4e38f; int bi = 0;
    #pragma unroll
    for (int k = 0; k < KCL; ++k) {
      int c = b * KCL + k;
      float dot = x * cc[c * 3] + y * cc[c * 3 + 1] + z * cc[c * 3 + 2];
      float d2 = fmaxf(n + cn[c] - 2.f * dot, 0.f);
      if (d2 < best) { best = d2; bi = k; }
    }
    atomicAdd(&sums[bi][0], x);
    atomicAdd(&sums[bi][1], y);
    atomicAdd(&sums[bi][2], z);
    atomicAdd(&cnts[bi], 1);
  }
  __syncthreads();
  if (t < KCL) {
    float c = (float)cnts[t];
    float inv = 1.f / fmaxf(c, 1.f);
    float ax = (cnts[t] > 0) ? sums[t][0] * inv : 0.f;
    float ay = (cnts[t] > 0) ? sums[t][1] * inv : 0.f;
    float az = (cnts[t] > 0) ? sums[t][2] * inv : 0.f;
    avg[t][0] = ax; avg[t][1] = ay; avg[t][2] = az;
    an[t] = ax * ax + ay * ay + az * az;
  }
  __syncthreads();
  if (t < KCL) {
    float x = c0[t * 3], y = c0[t * 3 + 1], z = c0[t * 3 + 2];
    float n = x * x + y * y + z * z;
    float best = 3.4e38f; int bi = 0;
    #pragma unroll
    for (int j = 0; j < KCL; ++j) {
      float dot = x * avg[j][0] + y * avg[j][1] + z * avg[j][2];
      float d2 = fmaxf(n + an[j] - 2.f * dot, 0.f);
      if (d2 < best) { best = d2; bi = j; }
    }
    float nx = 0.8f * x + 0.2f * avg[bi][0];
    float ny = 0.8f * y + 0.2f * avg[bi][1];
    float nz = 0.8f * z + 0.2f * avg[bi][2];
    c1x[t] = nx; c1y[t] = ny; c1z[t] = nz;
    c1n[t] = nx * nx + ny * ny + nz * nz;
  }
  __syncthreads();
  {
    float x = pe[t * 3], y = pe[t * 3 + 1], z = pe[t * 3 + 2];
    float n = x * x + y * y + z * z;
    float v[KCL];
    #pragma unroll
    for (int k = 0; k < KCL; ++k) {
      float dot = x * c1x[k] + y * c1y[k] + z * c1z[k];
      v[k] = fmaxf(n + c1n[k] - 2.f * dot, 0.f);
    }
    bool used[KCL];
    #pragma unroll
    for (int k = 0; k < KCL; ++k) used[k] = false;
    for (int r = 0; r < KCL; ++r) {
      float best = 3.4e38f; int bi = 0;
      #pragma unroll
      for (int j = 0; j < KCL; ++j) {
        if (!used[j] && v[j] < best) { best = v[j]; bi = j; }
      }
      order[t][r] = bi;
      used[bi] = true;
    }
  }
  __syncthreads();
  if (t < 64) {
    int cnt = 0;
    int cur = (t < KCL) ? order[0][t] : 0;
    for (int i = 0; i < NC; ++i) {
      int nxt = (t < KCL && i + 1 < NC) ? order[i + 1][t] : 0;
      int ccur = __shfl(cnt, cur);
      bool avail = (t < KCL) && (ccur < 16);
      unsigned long long m = __ballot(avail);
      int chosen;
      if (m != 0ull) {
        int rank = __ffsll((unsigned long long)m) - 1;
        chosen = __shfl(cur, rank);
      } else {
        chosen = __shfl(cur, 0);
      }
      if (t == chosen) cnt++;
      if (t == 0) outp[i] = chosen;
      cur = nxt;
    }
  }
}

extern "C" void kernel_launch(void* const* d_in, const int* in_sizes, int n_in,
                              void* d_out, int out_size, void* d_ws, size_t ws_size,
                              hipStream_t stream) {
  (void)in_sizes; (void)n_in; (void)out_size; (void)ws_size;
  const float* features = (const float*)d_in[0];
  const float* pe = (const float*)d_in[1];
  char* ws = (char*)d_ws;
  float* Pp       = (float*)(ws);                  // 16*8*256*256*4 = 32 MiB
  float* Db       = (float*)(ws + 33554432);       // 2 MiB
  float* rs       = (float*)(ws + 35651584);       // 8 KiB
  float* centers0 = (float*)(ws + 35659776);       // 192 B
  float* ccoord   = (float*)(ws + 35660288);       // 1.5 KiB
  int*   outp     = (int*)d_out;

  hipLaunchKernelGGL(k_gemm_pre, dim3(GEMM_BLOCKS + 1), dim3(256), 0, stream,
                     features, pe, Pp, centers0, rs);
  hipLaunchKernelGGL(k_formD, dim3(256), dim3(256), 0, stream, Pp, Db, rs);
  hipLaunchKernelGGL(k_fps_b, dim3(NB), dim3(256), 0, stream, Db, rs, pe, ccoord);
  hipLaunchKernelGGL(k_final, dim3(1), dim3(256), 0, stream, pe, ccoord, centers0, outp);
}